// Round 2
// baseline (122.501 us; speedup 1.0000x reference)
//
#include <hip/hip_runtime.h>

// Multivariate Hawkes process log-likelihood, N=8192 events, D=10 types.
// Dominant cost: 33.5M pairwise exp evaluations (strict lower triangle).
//
// 2-dispatch structure (no memsets, no atomics):
//   hawkes_pairs : grid(32,32) lower-tri blocks; block (ib,jb) writes its
//                  256 per-i partial sums to partial[jb*8192 + i]. Each slot
//                  written exactly once; jb>ib slots never read (poison-safe).
//   hawkes_finish: ONE 1024-thread block; per-i log-intensity minus integral
//                  tail, block reduction, single store to out[0].
//
// ws layout (floats): [0, 32*8192) partial sums.

#define N_EV 8192
#define DT 10

__device__ __forceinline__ float fast_exp2(float x) {
#if __has_builtin(__builtin_amdgcn_exp2f)
    return __builtin_amdgcn_exp2f(x);
#else
    return exp2f(x);
#endif
}

// jax.nn.softplus(x) = max(x,0) + log1p(exp(-|x|))
__device__ __forceinline__ float softplus(float x) {
    return fmaxf(x, 0.0f) + log1pf(expf(-fabsf(x)));
}

// T arrives as a 1-element array of unknown encoding (python int scalar).
// If the float32 interpretation is plausible use it, else the int32 one.
__device__ __forceinline__ float read_T(const void* p) {
    float f = *(const float*)p;
    if (f > 0.5f && f < 1.0e9f) return f;
    return (float)(*(const int*)p);
}

// Phase A: pairwise sums. Block (jb, ib) handles i in [ib*256, ib*256+256),
// j in [jb*256, jb*256+256), strictly lower triangular (j < i).
__global__ __launch_bounds__(256) void hawkes_pairs(
        const float* __restrict__ tp, const int* __restrict__ et,
        const float* __restrict__ la, const float* __restrict__ lb,
        float* __restrict__ partial) {
    const int ib = blockIdx.y, jb = blockIdx.x;
    if (jb > ib) return;

    __shared__ float2 te_s[256];          // (t_j, e_j-as-float-bits)
    __shared__ float2 tab_s[DT * DT];     // (nbl2, ab)

    const int tid = threadIdx.x;
    if (tid < DT * DT) {
        float a = softplus(la[tid]);
        float b = softplus(lb[tid]);
        tab_s[tid] = make_float2(-b * 1.4426950408889634f, a * b);
    }
    const int j0 = jb << 8;
    te_s[tid] = make_float2(tp[j0 + tid], __int_as_float(et[j0 + tid]));
    __syncthreads();

    const int i = (ib << 8) + tid;
    const float ti = tp[i];
    const int rowb = et[i] * DT;
    const int cnt = (ib == jb) ? tid : 256;   // strict j < i on the diagonal

    float a0 = 0.0f, a1 = 0.0f;
    int j = 0;
#pragma unroll 2
    for (; j + 2 <= cnt; j += 2) {
        float2 te0 = te_s[j];
        float2 te1 = te_s[j + 1];
        float2 tb0 = tab_s[rowb + __float_as_int(te0.y)];
        float2 tb1 = tab_s[rowb + __float_as_int(te1.y)];
        a0 = fmaf(tb0.y, fast_exp2(tb0.x * (ti - te0.x)), a0);
        a1 = fmaf(tb1.y, fast_exp2(tb1.x * (ti - te1.x)), a1);
    }
    if (j < cnt) {
        float2 te0 = te_s[j];
        float2 tb0 = tab_s[rowb + __float_as_int(te0.y)];
        a0 = fmaf(tb0.y, fast_exp2(tb0.x * (ti - te0.x)), a0);
    }
    partial[(jb << 13) + i] = a0 + a1;    // one writer per slot, no init needed
}

// Phase B: single block. Per-event log-intensity minus integral tail,
// block-wide reduction, single store (no atomics, no pre-zeroed out).
__global__ __launch_bounds__(1024) void hawkes_finish(
        const float* __restrict__ tp, const int* __restrict__ et,
        const float* __restrict__ mu, const float* __restrict__ la,
        const float* __restrict__ lb, const void* __restrict__ Tp,
        const float* __restrict__ partial, float* __restrict__ out) {
    __shared__ float mu_s[DT];
    __shared__ float alpha_s[DT * DT];
    __shared__ float nbl2_s[DT * DT];

    const int tid = threadIdx.x;
    if (tid < DT * DT) {
        alpha_s[tid] = softplus(la[tid]);
        nbl2_s[tid]  = -softplus(lb[tid]) * 1.4426950408889634f;
    }
    if (tid >= 128 && tid < 128 + DT) mu_s[tid - 128] = softplus(mu[tid - 128]);
    __syncthreads();

    const float Tf = read_T(Tp);
    float val = 0.0f;

    for (int i = tid; i < N_EV; i += 1024) {
        const int ib = i >> 8;
        float acc = 0.0f;
        for (int jb = 0; jb <= ib; ++jb) acc += partial[(jb << 13) + i];

        const int e = et[i];
        const float inten = mu_s[e] + acc;
        float v = logf(inten);

        const float delta = Tf - tp[i];
#pragma unroll
        for (int d = 0; d < DT; ++d)
            v -= alpha_s[d * DT + e] * (1.0f - fast_exp2(nbl2_s[d * DT + e] * delta));
        val += v;
    }

    if (tid == 0) {
        float s = 0.0f;
#pragma unroll
        for (int d = 0; d < DT; ++d) s += mu_s[d];
        val -= s * Tf;   // -T * sum(mu_s)
    }

    // wave reduce (64 lanes) then cross-wave via LDS
    for (int o = 32; o > 0; o >>= 1) val += __shfl_down(val, o);
    __shared__ float wsum[16];
    const int lane = tid & 63, wv = tid >> 6;
    if (lane == 0) wsum[wv] = val;
    __syncthreads();
    if (tid == 0) {
        float s = 0.0f;
#pragma unroll
        for (int w = 0; w < 16; ++w) s += wsum[w];
        out[0] = s;
    }
}

extern "C" void kernel_launch(void* const* d_in, const int* in_sizes, int n_in,
                              void* d_out, int out_size, void* d_ws, size_t ws_size,
                              hipStream_t stream) {
    const float* tp = (const float*)d_in[0];
    const int*   et = (const int*)d_in[1];
    const float* mu = (const float*)d_in[2];
    const float* la = (const float*)d_in[3];
    const float* lb = (const float*)d_in[4];
    const void*  Tp = d_in[5];
    float* out = (float*)d_out;
    float* ws  = (float*)d_ws;

    dim3 grid(32, 32);
    hawkes_pairs<<<grid, 256, 0, stream>>>(tp, et, la, lb, ws);
    hawkes_finish<<<1, 1024, 0, stream>>>(tp, et, mu, la, lb, Tp, ws, out);
}

// Round 5
// 82.724 us; speedup vs baseline: 1.4809x; 1.4809x over previous
//
#include <hip/hip_runtime.h>

// Multivariate Hawkes log-likelihood, N=8192, D=10.
// Pair term rewritten: ab*exp(-b*(ti-tj)) = exp2(P*ti + L),
//   P = -b*log2(e) (depends on (e_i, e_j)), L = log2(a*b) - P*t_j.
// Per j-tile we precompute (P,L) for all 10 possible e_i rows -> one
// ds_read_b64 + fma + exp2 + add per pair in the hot loop.
//
// 2 dispatches:
//   hawkes_pairs : grid(32,32) lower-tri; block (ib,jb) writes 256 partial
//                  sums to partial[jb*8192+i] (single writer, poison-safe).
//                  Block (0,0) also zeroes out[0] (stream order protects it).
//   hawkes_finish: 32 blocks x 256 thr; per-i log-intensity minus integral
//                  tail, block reduce, atomicAdd into out[0].

#define N_EV 8192
#define DT 10
#define LOG2E 1.4426950408889634f
#define TPAD 257   // pad so the 10 row base addresses hit distinct bank pairs

__device__ __forceinline__ float fast_exp2(float x) {
#if __has_builtin(__builtin_amdgcn_exp2f)
    return __builtin_amdgcn_exp2f(x);
#else
    return exp2f(x);
#endif
}

// jax.nn.softplus(x) = max(x,0) + log1p(exp(-|x|))
__device__ __forceinline__ float softplus(float x) {
    return fmaxf(x, 0.0f) + log1pf(expf(-fabsf(x)));
}

// T arrives as a 1-element array of unknown encoding (python int scalar).
__device__ __forceinline__ float read_T(const void* p) {
    float f = *(const float*)p;
    if (f > 0.5f && f < 1.0e9f) return f;
    return (float)(*(const int*)p);
}

__global__ __launch_bounds__(256) void hawkes_pairs(
        const float* __restrict__ tp, const int* __restrict__ et,
        const float* __restrict__ la, const float* __restrict__ lb,
        float* __restrict__ partial, float* __restrict__ out) {
    const int ib = blockIdx.y, jb = blockIdx.x;
    if (jb > ib) return;

    __shared__ float  nbl2_s[DT * DT];
    __shared__ float  lab_s[DT * DT];
    __shared__ float2 tile[DT][TPAD];   // (P, L) per (row r, tile index j)

    const int tid = threadIdx.x;
    if (tid < DT * DT) {
        float a = softplus(la[tid]);
        float b = softplus(lb[tid]);
        nbl2_s[tid] = -b * LOG2E;
        lab_s[tid]  = log2f(a * b);
    }
    __syncthreads();

    const int j0 = jb << 8;
    {
        const float tj = tp[j0 + tid];
        const int   ej = et[j0 + tid];
#pragma unroll
        for (int r = 0; r < DT; ++r) {
            float P = nbl2_s[r * DT + ej];
            float L = fmaf(-P, tj, lab_s[r * DT + ej]);
            tile[r][tid] = make_float2(P, L);
        }
    }
    __syncthreads();

    const int i = (ib << 8) + tid;
    const float ti = tp[i];
    const float2* __restrict__ trow = tile[et[i]];
    const int cnt = (ib == jb) ? tid : 256;   // strict j < i on the diagonal

    float a0 = 0.0f, a1 = 0.0f, a2 = 0.0f, a3 = 0.0f;
    int j = 0;
    for (; j + 4 <= cnt; j += 4) {
        float2 c0 = trow[j];
        float2 c1 = trow[j + 1];
        float2 c2 = trow[j + 2];
        float2 c3 = trow[j + 3];
        a0 += fast_exp2(fmaf(c0.x, ti, c0.y));
        a1 += fast_exp2(fmaf(c1.x, ti, c1.y));
        a2 += fast_exp2(fmaf(c2.x, ti, c2.y));
        a3 += fast_exp2(fmaf(c3.x, ti, c3.y));
    }
    for (; j < cnt; ++j) {
        float2 c0 = trow[j];
        a0 += fast_exp2(fmaf(c0.x, ti, c0.y));
    }
    partial[(jb << 13) + i] = (a0 + a1) + (a2 + a3);

    if (ib == 0 && jb == 0 && tid == 0) out[0] = 0.0f;  // finish atomicAdds later
}

__global__ __launch_bounds__(256) void hawkes_finish(
        const float* __restrict__ tp, const int* __restrict__ et,
        const float* __restrict__ mu, const float* __restrict__ la,
        const float* __restrict__ lb, const void* __restrict__ Tp,
        const float* __restrict__ partial, float* __restrict__ out) {
    __shared__ float mu_s[DT];
    __shared__ float alpha_s[DT * DT];
    __shared__ float nbl2_s[DT * DT];

    const int tid = threadIdx.x;
    if (tid < DT * DT) {
        alpha_s[tid] = softplus(la[tid]);
        nbl2_s[tid]  = -softplus(lb[tid]) * LOG2E;
    }
    if (tid >= 128 && tid < 128 + DT) mu_s[tid - 128] = softplus(mu[tid - 128]);
    __syncthreads();

    const int b = blockIdx.x;
    const int i = (b << 8) + tid;
    const float Tf = read_T(Tp);

    float acc = 0.0f;
    for (int jb = 0; jb <= b; ++jb) acc += partial[(jb << 13) + i];

    const int e = et[i];
    float val = logf(mu_s[e] + acc);

    const float delta = Tf - tp[i];
#pragma unroll
    for (int d = 0; d < DT; ++d)
        val -= alpha_s[d * DT + e] * (1.0f - fast_exp2(nbl2_s[d * DT + e] * delta));

    if (i == 0) {
        float s = 0.0f;
#pragma unroll
        for (int d = 0; d < DT; ++d) s += mu_s[d];
        val -= s * Tf;   // -T * sum(mu_s)
    }

    // wave reduce (64 lanes) then cross-wave via LDS
    for (int o = 32; o > 0; o >>= 1) val += __shfl_down(val, o);
    __shared__ float wsum[4];
    const int lane = tid & 63, wv = tid >> 6;
    if (lane == 0) wsum[wv] = val;
    __syncthreads();
    if (tid == 0) atomicAdd(out, wsum[0] + wsum[1] + wsum[2] + wsum[3]);
}

extern "C" void kernel_launch(void* const* d_in, const int* in_sizes, int n_in,
                              void* d_out, int out_size, void* d_ws, size_t ws_size,
                              hipStream_t stream) {
    const float* tp = (const float*)d_in[0];
    const int*   et = (const int*)d_in[1];
    const float* mu = (const float*)d_in[2];
    const float* la = (const float*)d_in[3];
    const float* lb = (const float*)d_in[4];
    const void*  Tp = d_in[5];
    float* out = (float*)d_out;
    float* ws  = (float*)d_ws;

    dim3 grid(32, 32);
    hawkes_pairs<<<grid, 256, 0, stream>>>(tp, et, la, lb, ws, out);
    hawkes_finish<<<32, 256, 0, stream>>>(tp, et, mu, la, lb, Tp, ws, out);
}